// Round 7
// baseline (449.857 us; speedup 1.0000x reference)
//
#include <hip/hip_runtime.h>
#include <math.h>

#define HH 512
#define WW 512
#define BB 32
#define CHUNK 16

__device__ __forceinline__ float min3f(float a, float b, float c) {
    return fminf(fminf(a, b), c);
}
__device__ __forceinline__ float max3f(float a, float b, float c) {
    return fmaxf(fmaxf(a, b), c);
}
__device__ __forceinline__ float4 ld4(const float* p, bool ok) {
    float4 v;
    if (ok) v = *(const float4*)p;
    else { v.x = INFINITY; v.y = INFINITY; v.z = INFINITY; v.w = INFINITY; }
    return v;
}

__device__ __forceinline__ void loadrow(const float* __restrict__ img, int R, int gx0,
                                        bool lok, bool rok, float* xr) {
    const bool rowok = (unsigned)R < HH;
    const float* rp = img + (size_t)R * WW + gx0;
    float4 v0 = ld4(rp - 4, rowok && lok);
    float4 v1 = ld4(rp,     rowok);
    float4 v2 = ld4(rp + 4, rowok && rok);
    xr[0] = v0.x; xr[1] = v0.y; xr[2] = v0.z; xr[3] = v0.w;
    xr[4] = v1.x; xr[5] = v1.y; xr[6] = v1.z; xr[7] = v1.w;
    xr[8] = v2.x; xr[9] = v2.y; xr[10] = v2.z; xr[11] = v2.w;
}

// Two fused soft-skeletonize iterations, register-pipelined, no LDS,
// fully unrolled row walk, depth-2 load prefetch.
// __launch_bounds__(256,3): cap VGPR at ~170 so 3 waves/SIMD stay resident
// (round-6's 220-VGPR allocation halved occupancy; a ~168-VGPR schedule of
// this computation exists without spills — round 5 produced one).
// FUSED=1: final pass accumulates acc0=sum(x2*companion), acc1=sum(x2).
template <int FUSED>
__global__ __launch_bounds__(256, 3) void skel2r_t(const float* __restrict__ srcA,
                                                   const float* __restrict__ srcB,
                                                   const float* __restrict__ cmpA,
                                                   const float* __restrict__ cmpB,
                                                   float* __restrict__ dst,
                                                   float* __restrict__ partials) {
    const int s = blockIdx.x * 64 + threadIdx.x;            // span 0..127
    const int y0 = (blockIdx.y * 4 + threadIdx.y) * CHUNK;  // output row start
    const int z = blockIdx.z;
    const float* img = (z < BB) ? (srcA + (size_t)z * (HH * WW))
                                : (srcB + (size_t)(z - BB) * (HH * WW));
    const float* cmp = nullptr;
    if (FUSED) cmp = (z < BB) ? (cmpA + (size_t)z * (HH * WW))
                              : (cmpB + (size_t)(z - BB) * (HH * WW));
    float* outp = FUSED ? nullptr : (dst + (size_t)z * (HH * WW));
    const int gx0 = 4 * s;
    const bool lok = (s > 0), rok = (s < 127);
    const bool isL = (s == 0), isR = (s == 127);

    // ring state (fully unrolled loop -> pure register renaming)
    float hm0a[10], hm0b[10], mn0p[8];
    float hx0a[8], hx0b[8];
    float x0a[8], x0b[8];
    float hm1a[6], hm1b[6], mn1p[4];
    float hx1a[4], hx1b[4];
    float x1a[4], x1b[4];

    #pragma unroll
    for (int i = 0; i < 10; ++i) { hm0a[i] = INFINITY; hm0b[i] = INFINITY; }
    #pragma unroll
    for (int j = 0; j < 8; ++j)  { mn0p[j] = -INFINITY; hx0a[j] = -INFINITY; hx0b[j] = -INFINITY; x0a[j] = INFINITY; x0b[j] = INFINITY; }
    #pragma unroll
    for (int k = 0; k < 6; ++k)  { hm1a[k] = INFINITY; hm1b[k] = INFINITY; }
    #pragma unroll
    for (int m = 0; m < 4; ++m)  { mn1p[m] = -INFINITY; hx1a[m] = -INFINITY; hx1b[m] = -INFINITY; x1a[m] = INFINITY; x1b[m] = INFINITY; }

    float acc0 = 0.0f, acc1 = 0.0f;

    // depth-2 prefetch: xA = row R, xB = row R+1, xC loaded for R+2
    float xA[12], xB[12];
    loadrow(img, y0 - 4, gx0, lok, rok, xA);
    loadrow(img, y0 - 3, gx0, lok, rok, xB);
    float4 cmpNext;
    cmpNext.x = 0.f; cmpNext.y = 0.f; cmpNext.z = 0.f; cmpNext.w = 0.f;

    #pragma unroll
    for (int rr = 0; rr < CHUNK + 8; ++rr) {
        const int R = y0 - 4 + rr;

        float xC[12];
        if (rr < CHUNK + 6) {
            loadrow(img, R + 2, gx0, lok, rok, xC);
        } else {
            #pragma unroll
            for (int i = 0; i < 12; ++i) xC[i] = INFINITY;  // dead, DCE'd
        }

        float4 cmpCur;
        if (FUSED) {
            cmpCur = cmpNext;
            if (rr >= 7 && rr < CHUNK + 7) {
                cmpNext = *(const float4*)(cmp + (size_t)(R - 3) * WW + gx0);
            }
        }

        // ---- iter1 horizontal min, row R ----
        float hm0c[10];
        #pragma unroll
        for (int i = 0; i < 10; ++i) hm0c[i] = min3f(xA[i], xA[i + 1], xA[i + 2]);

        // ---- iter1 min-pool row R-1 ----
        float mn0n[10];
        #pragma unroll
        for (int i = 0; i < 10; ++i) mn0n[i] = min3f(hm0a[i], hm0b[i], hm0c[i]);
        if (!((unsigned)(R - 1) < HH)) {        // wave-uniform, rarely taken
            #pragma unroll
            for (int i = 0; i < 10; ++i) mn0n[i] = -INFINITY;
        }
        if (isL) { mn0n[0] = -INFINITY; mn0n[1] = -INFINITY; mn0n[2] = -INFINITY; }
        if (isR) { mn0n[7] = -INFINITY; mn0n[8] = -INFINITY; mn0n[9] = -INFINITY; }

        // ---- horiz max of mn0 row R-1 ----
        float hx0n[8];
        #pragma unroll
        for (int j = 0; j < 8; ++j) hx0n[j] = max3f(mn0n[j], mn0n[j + 1], mn0n[j + 2]);

        // ---- iter1 update: x1 row R-2 ----
        float x1n[8];
        #pragma unroll
        for (int j = 0; j < 8; ++j) {
            float mp = max3f(hx0a[j], hx0b[j], hx0n[j]);
            float ct = fmaxf(mp - mn0p[j], 0.0f);
            x1n[j] = fmaxf(x0a[j] - ct, 0.0f);
        }
        if (!((unsigned)(R - 2) < HH)) {
            #pragma unroll
            for (int j = 0; j < 8; ++j) x1n[j] = INFINITY;
        }
        if (isL) { x1n[0] = INFINITY; x1n[1] = INFINITY; }
        if (isR) { x1n[6] = INFINITY; x1n[7] = INFINITY; }

        // ---- iter2 horizontal min, row R-2 ----
        float hm1n[6];
        #pragma unroll
        for (int k = 0; k < 6; ++k) hm1n[k] = min3f(x1n[k], x1n[k + 1], x1n[k + 2]);

        // ---- iter2 min-pool row R-3 ----
        float mn1n[6];
        #pragma unroll
        for (int k = 0; k < 6; ++k) mn1n[k] = min3f(hm1a[k], hm1b[k], hm1n[k]);
        if (!((unsigned)(R - 3) < HH)) {
            #pragma unroll
            for (int k = 0; k < 6; ++k) mn1n[k] = -INFINITY;
        }
        if (isL) mn1n[0] = -INFINITY;
        if (isR) mn1n[5] = -INFINITY;

        // ---- horiz max of mn1 row R-3 ----
        float hx1n[4];
        #pragma unroll
        for (int m = 0; m < 4; ++m) hx1n[m] = max3f(mn1n[m], mn1n[m + 1], mn1n[m + 2]);

        // ---- iter2 update: x2 row R-4 ----
        if (rr >= 8) {
            float o[4];
            #pragma unroll
            for (int m = 0; m < 4; ++m) {
                float mp = max3f(hx1a[m], hx1b[m], hx1n[m]);
                float ct = fmaxf(mp - mn1p[m], 0.0f);
                o[m] = fmaxf(x1a[m] - ct, 0.0f);
            }
            if (FUSED) {
                acc0 += o[0] * cmpCur.x + o[1] * cmpCur.y + o[2] * cmpCur.z + o[3] * cmpCur.w;
                acc1 += o[0] + o[1] + o[2] + o[3];
            } else {
                float4 ov;
                ov.x = o[0]; ov.y = o[1]; ov.z = o[2]; ov.w = o[3];
                *(float4*)(outp + (size_t)(R - 4) * WW + gx0) = ov;
            }
        }

        // ---- ring shifts (free after full unroll) ----
        #pragma unroll
        for (int i = 0; i < 10; ++i) { hm0a[i] = hm0b[i]; hm0b[i] = hm0c[i]; }
        #pragma unroll
        for (int j = 0; j < 8; ++j)  { mn0p[j] = mn0n[j + 1]; hx0a[j] = hx0b[j]; hx0b[j] = hx0n[j]; x0a[j] = x0b[j]; x0b[j] = xA[j + 2]; }
        #pragma unroll
        for (int k = 0; k < 6; ++k)  { hm1a[k] = hm1b[k]; hm1b[k] = hm1n[k]; }
        #pragma unroll
        for (int m = 0; m < 4; ++m)  { mn1p[m] = mn1n[m + 1]; hx1a[m] = hx1b[m]; hx1b[m] = hx1n[m]; x1a[m] = x1b[m]; x1b[m] = x1n[m + 2]; }
        #pragma unroll
        for (int i = 0; i < 12; ++i) { xA[i] = xB[i]; xB[i] = xC[i]; }
    }

    if (FUSED) {
        for (int off = 32; off; off >>= 1) {
            acc0 += __shfl_down(acc0, off);
            acc1 += __shfl_down(acc1, off);
        }
        __shared__ float red[4][2];
        if (threadIdx.x == 0) { red[threadIdx.y][0] = acc0; red[threadIdx.y][1] = acc1; }
        __syncthreads();
        if (threadIdx.x == 0 && threadIdx.y == 0) {
            const int tile = blockIdx.x * gridDim.y + blockIdx.y;  // 0..15
            float* p = partials + ((size_t)z * 16 + tile) * 2;
            p[0] = red[0][0] + red[1][0] + red[2][0] + red[3][0];
            p[1] = red[0][1] + red[1][1] + red[2][1] + red[3][1];
        }
    }
}

// partials layout: [z][16 tiles][2]; z<32: (sum clp*tgt, sum clp); z>=32: (sum skt*prd, sum skt)
__global__ __launch_bounds__(64) void finalize2(const float* __restrict__ partials,
                                                float* __restrict__ out) {
    const int b = threadIdx.x;
    float iflat = 0.f, tflat = 0.f;
    if (b < BB) {
        float v0 = 0.f, v1 = 0.f, v2 = 0.f, v3 = 0.f;
        for (int t = 0; t < 16; ++t) {
            v0 += partials[((size_t)b * 16 + t) * 2 + 0];
            v1 += partials[((size_t)b * 16 + t) * 2 + 1];
            v2 += partials[((size_t)(b + BB) * 16 + t) * 2 + 0];
            v3 += partials[((size_t)(b + BB) * 16 + t) * 2 + 1];
        }
        iflat = (v0 + 1e-6f) / (v1 + 1e-6f);
        tflat = (v2 + 1e-6f) / (v3 + 1e-6f);
    }
    float prod = iflat * tflat;
    float ssum = iflat + tflat;
    for (int off = 32; off; off >>= 1) {
        prod += __shfl_down(prod, off);
        ssum += __shfl_down(ssum, off);
    }
    if (threadIdx.x == 0) out[0] = 1.0f - 2.0f * prod / ssum;
}

extern "C" void kernel_launch(void* const* d_in, const int* in_sizes, int n_in,
                              void* d_out, int out_size, void* d_ws, size_t ws_size,
                              hipStream_t stream) {
    const float* pred = (const float*)d_in[0];
    const float* target = (const float*)d_in[1];
    float* out = (float*)d_out;
    char* ws = (char*)d_ws;
    const size_t N = (size_t)HH * WW;
    const size_t HALF = (size_t)BB * N;                 // 32 imgs of floats
    const size_t IMG32 = HALF * sizeof(float);          // 32 MB

    dim3 block(64, 4);
    const int nby = HH / (CHUNK * 4);                   // 8

    if (ws_size >= 4 * IMG32 + (1 << 16)) {
        // z=64 path: both chains per dispatch, ping-pong 64MB buffers A<->B
        float* A = (float*)ws;
        float* B = (float*)(ws + 2 * IMG32);
        float* partials = (float*)(ws + 4 * IMG32);     // 64*16*2 floats
        dim3 grid(2, nby, 2 * BB);
        skel2r_t<0><<<grid, block, 0, stream>>>(pred, target, nullptr, nullptr, A, nullptr);
        skel2r_t<0><<<grid, block, 0, stream>>>(A, A + HALF, nullptr, nullptr, B, nullptr);
        skel2r_t<0><<<grid, block, 0, stream>>>(B, B + HALF, nullptr, nullptr, A, nullptr);
        skel2r_t<0><<<grid, block, 0, stream>>>(A, A + HALF, nullptr, nullptr, B, nullptr);
        // final pass fused with reduction: z<32 companion=target, z>=32 companion=pred
        skel2r_t<1><<<grid, block, 0, stream>>>(B, B + HALF, target, pred, nullptr, partials);
        finalize2<<<1, 64, 0, stream>>>(partials, out);
    } else {
        // fallback: z=32 path with 2x32MB buffers, fused final pass per chain
        float* b0 = (float*)ws;
        float* b1 = (float*)(ws + IMG32);
        float* partials = (float*)(ws + 2 * IMG32);
        dim3 grid(2, nby, BB);
        skel2r_t<0><<<grid, block, 0, stream>>>(pred, pred, nullptr, nullptr, b0, nullptr);
        skel2r_t<0><<<grid, block, 0, stream>>>(b0, b0, nullptr, nullptr, b1, nullptr);
        skel2r_t<0><<<grid, block, 0, stream>>>(b1, b1, nullptr, nullptr, b0, nullptr);
        skel2r_t<0><<<grid, block, 0, stream>>>(b0, b0, nullptr, nullptr, b1, nullptr);
        skel2r_t<1><<<grid, block, 0, stream>>>(b1, b1, target, target, nullptr, partials);
        skel2r_t<0><<<grid, block, 0, stream>>>(target, target, nullptr, nullptr, b0, nullptr);
        skel2r_t<0><<<grid, block, 0, stream>>>(b0, b0, nullptr, nullptr, b1, nullptr);
        skel2r_t<0><<<grid, block, 0, stream>>>(b1, b1, nullptr, nullptr, b0, nullptr);
        skel2r_t<0><<<grid, block, 0, stream>>>(b0, b0, nullptr, nullptr, b1, nullptr);
        skel2r_t<1><<<grid, block, 0, stream>>>(b1, b1, pred, pred, nullptr,
                                                partials + (size_t)BB * 16 * 2);
        finalize2<<<1, 64, 0, stream>>>(partials, out);
    }
}

// Round 8
// 174.570 us; speedup vs baseline: 2.5769x; 2.5769x over previous
//
#include <hip/hip_runtime.h>
#include <math.h>

#define HH 512
#define WW 512
#define BB 32
#define CHUNK 32

__device__ __forceinline__ float min3f(float a, float b, float c) {
    return fminf(fminf(a, b), c);
}
__device__ __forceinline__ float max3f(float a, float b, float c) {
    return fmaxf(fmaxf(a, b), c);
}
__device__ __forceinline__ float4 ld4(const float* p, bool ok) {
    float4 v;
    if (ok) v = *(const float4*)p;
    else { v.x = INFINITY; v.y = INFINITY; v.z = INFINITY; v.w = INFINITY; }
    return v;
}

__device__ __forceinline__ void loadrow(const float* __restrict__ img, int R, int gx0,
                                        bool lok, bool rok, float* xr) {
    const bool rowok = (unsigned)R < HH;
    const float* rp = img + (size_t)R * WW + gx0;
    float4 v0 = ld4(rp - 4, rowok && lok);
    float4 v1 = ld4(rp,     rowok);
    float4 v2 = ld4(rp + 4, rowok && rok);
    xr[0] = v0.x; xr[1] = v0.y; xr[2] = v0.z; xr[3] = v0.w;
    xr[4] = v1.x; xr[5] = v1.y; xr[6] = v1.z; xr[7] = v1.w;
    xr[8] = v2.x; xr[9] = v2.y; xr[10] = v2.z; xr[11] = v2.w;
}

// Two fused soft-skeletonize iterations, register-pipelined, no LDS,
// fully unrolled 40-row walk (CHUNK=32: 1.25x row overhead vs 1.5x at 16),
// depth-2 img prefetch, depth-3 companion prefetch in the fused pass.
// NOTE: no min-waves launch_bounds — VGPR occupancy steps at 64/128/256;
// forcing 3 waves/EU (round 7) spilled ~325 MB/dispatch to scratch.
// FUSED=1: final pass accumulates acc0=sum(x2*companion), acc1=sum(x2).
template <int FUSED>
__global__ __launch_bounds__(256) void skel2r_t(const float* __restrict__ srcA,
                                                const float* __restrict__ srcB,
                                                const float* __restrict__ cmpA,
                                                const float* __restrict__ cmpB,
                                                float* __restrict__ dst,
                                                float* __restrict__ partials) {
    const int s = blockIdx.x * 64 + threadIdx.x;            // span 0..127
    const int y0 = (blockIdx.y * 4 + threadIdx.y) * CHUNK;  // output row start
    const int z = blockIdx.z;
    const float* img = (z < BB) ? (srcA + (size_t)z * (HH * WW))
                                : (srcB + (size_t)(z - BB) * (HH * WW));
    const float* cmp = nullptr;
    if (FUSED) cmp = (z < BB) ? (cmpA + (size_t)z * (HH * WW))
                              : (cmpB + (size_t)(z - BB) * (HH * WW));
    float* outp = FUSED ? nullptr : (dst + (size_t)z * (HH * WW));
    const int gx0 = 4 * s;
    const bool lok = (s > 0), rok = (s < 127);
    const bool isL = (s == 0), isR = (s == 127);

    // ring state (fully unrolled loop -> pure register renaming)
    float hm0a[10], hm0b[10], mn0p[8];
    float hx0a[8], hx0b[8];
    float x0a[8], x0b[8];
    float hm1a[6], hm1b[6], mn1p[4];
    float hx1a[4], hx1b[4];
    float x1a[4], x1b[4];

    #pragma unroll
    for (int i = 0; i < 10; ++i) { hm0a[i] = INFINITY; hm0b[i] = INFINITY; }
    #pragma unroll
    for (int j = 0; j < 8; ++j)  { mn0p[j] = -INFINITY; hx0a[j] = -INFINITY; hx0b[j] = -INFINITY; x0a[j] = INFINITY; x0b[j] = INFINITY; }
    #pragma unroll
    for (int k = 0; k < 6; ++k)  { hm1a[k] = INFINITY; hm1b[k] = INFINITY; }
    #pragma unroll
    for (int m = 0; m < 4; ++m)  { mn1p[m] = -INFINITY; hx1a[m] = -INFINITY; hx1b[m] = -INFINITY; x1a[m] = INFINITY; x1b[m] = INFINITY; }

    float acc0 = 0.0f, acc1 = 0.0f;

    // depth-2 prefetch: xA = row R, xB = row R+1, xC loaded for R+2
    float xA[12], xB[12];
    loadrow(img, y0 - 4, gx0, lok, rok, xA);
    loadrow(img, y0 - 3, gx0, lok, rok, xB);
    // depth-3 companion ring: cmpQ0 consumed at rr, cmpQ2 loaded at rr for rr+3
    float4 cmpQ0, cmpQ1, cmpQ2;
    cmpQ0.x = cmpQ0.y = cmpQ0.z = cmpQ0.w = 0.f;
    cmpQ1 = cmpQ0; cmpQ2 = cmpQ0;

    #pragma unroll
    for (int rr = 0; rr < CHUNK + 8; ++rr) {
        const int R = y0 - 4 + rr;

        float xC[12];
        if (rr < CHUNK + 6) {
            loadrow(img, R + 2, gx0, lok, rok, xC);
        } else {
            #pragma unroll
            for (int i = 0; i < 12; ++i) xC[i] = INFINITY;  // dead, DCE'd
        }

        float4 cmpCur;
        if (FUSED) {
            cmpCur = cmpQ0;
            cmpQ0 = cmpQ1; cmpQ1 = cmpQ2;                    // free after unroll
            if (rr >= 5 && rr < CHUNK + 5) {
                // row (R-1) = output row consumed 3 iterations later
                cmpQ2 = *(const float4*)(cmp + (size_t)(R - 1) * WW + gx0);
            }
        }

        // ---- iter1 horizontal min, row R ----
        float hm0c[10];
        #pragma unroll
        for (int i = 0; i < 10; ++i) hm0c[i] = min3f(xA[i], xA[i + 1], xA[i + 2]);

        // ---- iter1 min-pool row R-1 ----
        float mn0n[10];
        #pragma unroll
        for (int i = 0; i < 10; ++i) mn0n[i] = min3f(hm0a[i], hm0b[i], hm0c[i]);
        if (!((unsigned)(R - 1) < HH)) {        // wave-uniform, rarely taken
            #pragma unroll
            for (int i = 0; i < 10; ++i) mn0n[i] = -INFINITY;
        }
        if (isL) { mn0n[0] = -INFINITY; mn0n[1] = -INFINITY; mn0n[2] = -INFINITY; }
        if (isR) { mn0n[7] = -INFINITY; mn0n[8] = -INFINITY; mn0n[9] = -INFINITY; }

        // ---- horiz max of mn0 row R-1 ----
        float hx0n[8];
        #pragma unroll
        for (int j = 0; j < 8; ++j) hx0n[j] = max3f(mn0n[j], mn0n[j + 1], mn0n[j + 2]);

        // ---- iter1 update: x1 row R-2 ----
        float x1n[8];
        #pragma unroll
        for (int j = 0; j < 8; ++j) {
            float mp = max3f(hx0a[j], hx0b[j], hx0n[j]);
            float ct = fmaxf(mp - mn0p[j], 0.0f);
            x1n[j] = fmaxf(x0a[j] - ct, 0.0f);
        }
        if (!((unsigned)(R - 2) < HH)) {
            #pragma unroll
            for (int j = 0; j < 8; ++j) x1n[j] = INFINITY;
        }
        if (isL) { x1n[0] = INFINITY; x1n[1] = INFINITY; }
        if (isR) { x1n[6] = INFINITY; x1n[7] = INFINITY; }

        // ---- iter2 horizontal min, row R-2 ----
        float hm1n[6];
        #pragma unroll
        for (int k = 0; k < 6; ++k) hm1n[k] = min3f(x1n[k], x1n[k + 1], x1n[k + 2]);

        // ---- iter2 min-pool row R-3 ----
        float mn1n[6];
        #pragma unroll
        for (int k = 0; k < 6; ++k) mn1n[k] = min3f(hm1a[k], hm1b[k], hm1n[k]);
        if (!((unsigned)(R - 3) < HH)) {
            #pragma unroll
            for (int k = 0; k < 6; ++k) mn1n[k] = -INFINITY;
        }
        if (isL) mn1n[0] = -INFINITY;
        if (isR) mn1n[5] = -INFINITY;

        // ---- horiz max of mn1 row R-3 ----
        float hx1n[4];
        #pragma unroll
        for (int m = 0; m < 4; ++m) hx1n[m] = max3f(mn1n[m], mn1n[m + 1], mn1n[m + 2]);

        // ---- iter2 update: x2 row R-4 ----
        if (rr >= 8) {
            float o[4];
            #pragma unroll
            for (int m = 0; m < 4; ++m) {
                float mp = max3f(hx1a[m], hx1b[m], hx1n[m]);
                float ct = fmaxf(mp - mn1p[m], 0.0f);
                o[m] = fmaxf(x1a[m] - ct, 0.0f);
            }
            if (FUSED) {
                acc0 += o[0] * cmpCur.x + o[1] * cmpCur.y + o[2] * cmpCur.z + o[3] * cmpCur.w;
                acc1 += o[0] + o[1] + o[2] + o[3];
            } else {
                float4 ov;
                ov.x = o[0]; ov.y = o[1]; ov.z = o[2]; ov.w = o[3];
                *(float4*)(outp + (size_t)(R - 4) * WW + gx0) = ov;
            }
        }

        // ---- ring shifts (free after full unroll) ----
        #pragma unroll
        for (int i = 0; i < 10; ++i) { hm0a[i] = hm0b[i]; hm0b[i] = hm0c[i]; }
        #pragma unroll
        for (int j = 0; j < 8; ++j)  { mn0p[j] = mn0n[j + 1]; hx0a[j] = hx0b[j]; hx0b[j] = hx0n[j]; x0a[j] = x0b[j]; x0b[j] = xA[j + 2]; }
        #pragma unroll
        for (int k = 0; k < 6; ++k)  { hm1a[k] = hm1b[k]; hm1b[k] = hm1n[k]; }
        #pragma unroll
        for (int m = 0; m < 4; ++m)  { mn1p[m] = mn1n[m + 1]; hx1a[m] = hx1b[m]; hx1b[m] = hx1n[m]; x1a[m] = x1b[m]; x1b[m] = x1n[m + 2]; }
        #pragma unroll
        for (int i = 0; i < 12; ++i) { xA[i] = xB[i]; xB[i] = xC[i]; }
    }

    if (FUSED) {
        for (int off = 32; off; off >>= 1) {
            acc0 += __shfl_down(acc0, off);
            acc1 += __shfl_down(acc1, off);
        }
        __shared__ float red[4][2];
        if (threadIdx.x == 0) { red[threadIdx.y][0] = acc0; red[threadIdx.y][1] = acc1; }
        __syncthreads();
        if (threadIdx.x == 0 && threadIdx.y == 0) {
            const int tile = blockIdx.x * gridDim.y + blockIdx.y;  // 0..7
            float* p = partials + ((size_t)z * 16 + tile) * 2;
            p[0] = red[0][0] + red[1][0] + red[2][0] + red[3][0];
            p[1] = red[0][1] + red[1][1] + red[2][1] + red[3][1];
        }
    }
}

// partials layout: [z][16 tile slots][2] (only first 2*nby used per z);
// z<32: (sum clp*tgt, sum clp); z>=32: (sum skt*prd, sum skt)
__global__ __launch_bounds__(64) void finalize2(const float* __restrict__ partials,
                                                int ntiles,
                                                float* __restrict__ out) {
    const int b = threadIdx.x;
    float iflat = 0.f, tflat = 0.f;
    if (b < BB) {
        float v0 = 0.f, v1 = 0.f, v2 = 0.f, v3 = 0.f;
        for (int t = 0; t < ntiles; ++t) {
            v0 += partials[((size_t)b * 16 + t) * 2 + 0];
            v1 += partials[((size_t)b * 16 + t) * 2 + 1];
            v2 += partials[((size_t)(b + BB) * 16 + t) * 2 + 0];
            v3 += partials[((size_t)(b + BB) * 16 + t) * 2 + 1];
        }
        iflat = (v0 + 1e-6f) / (v1 + 1e-6f);
        tflat = (v2 + 1e-6f) / (v3 + 1e-6f);
    }
    float prod = iflat * tflat;
    float ssum = iflat + tflat;
    for (int off = 32; off; off >>= 1) {
        prod += __shfl_down(prod, off);
        ssum += __shfl_down(ssum, off);
    }
    if (threadIdx.x == 0) out[0] = 1.0f - 2.0f * prod / ssum;
}

extern "C" void kernel_launch(void* const* d_in, const int* in_sizes, int n_in,
                              void* d_out, int out_size, void* d_ws, size_t ws_size,
                              hipStream_t stream) {
    const float* pred = (const float*)d_in[0];
    const float* target = (const float*)d_in[1];
    float* out = (float*)d_out;
    char* ws = (char*)d_ws;
    const size_t N = (size_t)HH * WW;
    const size_t HALF = (size_t)BB * N;                 // 32 imgs of floats
    const size_t IMG32 = HALF * sizeof(float);          // 32 MB

    dim3 block(64, 4);
    const int nby = HH / (CHUNK * 4);                   // 4
    const int ntiles = 2 * nby;                         // 8

    if (ws_size >= 4 * IMG32 + (1 << 16)) {
        // z=64 path: both chains per dispatch, ping-pong 64MB buffers A<->B
        float* A = (float*)ws;
        float* B = (float*)(ws + 2 * IMG32);
        float* partials = (float*)(ws + 4 * IMG32);     // 64*16*2 floats
        dim3 grid(2, nby, 2 * BB);
        skel2r_t<0><<<grid, block, 0, stream>>>(pred, target, nullptr, nullptr, A, nullptr);
        skel2r_t<0><<<grid, block, 0, stream>>>(A, A + HALF, nullptr, nullptr, B, nullptr);
        skel2r_t<0><<<grid, block, 0, stream>>>(B, B + HALF, nullptr, nullptr, A, nullptr);
        skel2r_t<0><<<grid, block, 0, stream>>>(A, A + HALF, nullptr, nullptr, B, nullptr);
        // final pass fused with reduction: z<32 companion=target, z>=32 companion=pred
        skel2r_t<1><<<grid, block, 0, stream>>>(B, B + HALF, target, pred, nullptr, partials);
        finalize2<<<1, 64, 0, stream>>>(partials, ntiles, out);
    } else {
        // fallback: z=32 path with 2x32MB buffers, fused final pass per chain
        float* b0 = (float*)ws;
        float* b1 = (float*)(ws + IMG32);
        float* partials = (float*)(ws + 2 * IMG32);
        dim3 grid(2, nby, BB);
        skel2r_t<0><<<grid, block, 0, stream>>>(pred, pred, nullptr, nullptr, b0, nullptr);
        skel2r_t<0><<<grid, block, 0, stream>>>(b0, b0, nullptr, nullptr, b1, nullptr);
        skel2r_t<0><<<grid, block, 0, stream>>>(b1, b1, nullptr, nullptr, b0, nullptr);
        skel2r_t<0><<<grid, block, 0, stream>>>(b0, b0, nullptr, nullptr, b1, nullptr);
        skel2r_t<1><<<grid, block, 0, stream>>>(b1, b1, target, target, nullptr, partials);
        skel2r_t<0><<<grid, block, 0, stream>>>(target, target, nullptr, nullptr, b0, nullptr);
        skel2r_t<0><<<grid, block, 0, stream>>>(b0, b0, nullptr, nullptr, b1, nullptr);
        skel2r_t<0><<<grid, block, 0, stream>>>(b1, b1, nullptr, nullptr, b0, nullptr);
        skel2r_t<0><<<grid, block, 0, stream>>>(b0, b0, nullptr, nullptr, b1, nullptr);
        skel2r_t<1><<<grid, block, 0, stream>>>(b1, b1, pred, pred, nullptr,
                                                partials + (size_t)BB * 16 * 2);
        finalize2<<<1, 64, 0, stream>>>(partials, ntiles, out);
    }
}

// Round 9
// 154.838 us; speedup vs baseline: 2.9053x; 1.1274x over previous
//
#include <hip/hip_runtime.h>
#include <math.h>

#define HH 512
#define WW 512
#define BB 32
#define CHUNK 32

__device__ __forceinline__ float min3f(float a, float b, float c) {
    return fminf(fminf(a, b), c);
}
__device__ __forceinline__ float max3f(float a, float b, float c) {
    return fmaxf(fmaxf(a, b), c);
}

// Unconditional clamped row load: row index clamped (wave-uniform SALU),
// column bases pre-clamped (loop-invariant). Correctness: duplicating an
// in-window value never changes a min; the only two pad elements that feed
// NON-masked min-pool outputs are xr[3] (col gx0-1, lane s==0) and xr[8]
// (col gx0+4, lane s==127) -> element-clamp them to xr[0]/xr[7]. All other
// pad elements feed mn/x1 positions forced to -INF/+INF downstream.
__device__ __forceinline__ void loadrowC(const float* __restrict__ img, int R,
                                         int cm4, int c0, int cp4,
                                         bool isL, bool isR, float* xr) {
    const int Rc = R < 0 ? 0 : (R > HH - 1 ? HH - 1 : R);   // wave-uniform
    const float* rb = img + (size_t)Rc * WW;
    float4 v0 = *(const float4*)(rb + cm4);
    float4 v1 = *(const float4*)(rb + c0);
    float4 v2 = *(const float4*)(rb + cp4);
    xr[0] = v0.x; xr[1] = v0.y; xr[2] = v0.z; xr[3] = v0.w;
    xr[4] = v1.x; xr[5] = v1.y; xr[6] = v1.z; xr[7] = v1.w;
    xr[8] = v2.x; xr[9] = v2.y; xr[10] = v2.z; xr[11] = v2.w;
    if (isL) xr[3] = xr[0];
    if (isR) xr[8] = xr[7];
}

// Two fused soft-skeletonize iterations, register-pipelined, no LDS,
// fully unrolled 40-row walk, depth-3 image prefetch, clamped (maskless)
// loads. Row-OOB fixups are wave-uniform branches (rarely taken); col-OOB
// fixups are 2-lane cndmasks. No min-waves launch_bounds (round 7: forcing
// 3 waves/EU spilled 325 MB/dispatch; occupancy steps at 64/128/256 VGPR).
// FUSED=1: final pass accumulates acc0=sum(x2*companion), acc1=sum(x2).
template <int FUSED>
__global__ __launch_bounds__(256) void skel2r_t(const float* __restrict__ srcA,
                                                const float* __restrict__ srcB,
                                                const float* __restrict__ cmpA,
                                                const float* __restrict__ cmpB,
                                                float* __restrict__ dst,
                                                float* __restrict__ partials) {
    const int s = blockIdx.x * 64 + threadIdx.x;            // span 0..127
    const int y0 = (blockIdx.y * 4 + threadIdx.y) * CHUNK;  // output row start
    const int z = blockIdx.z;
    const float* img = (z < BB) ? (srcA + (size_t)z * (HH * WW))
                                : (srcB + (size_t)(z - BB) * (HH * WW));
    const float* cmp = nullptr;
    if (FUSED) cmp = (z < BB) ? (cmpA + (size_t)z * (HH * WW))
                              : (cmpB + (size_t)(z - BB) * (HH * WW));
    float* outp = FUSED ? nullptr : (dst + (size_t)z * (HH * WW));
    const int gx0 = 4 * s;
    const bool isL = (s == 0), isR = (s == 127);
    const int cm4 = isL ? 0 : gx0 - 4;      // clamped left-load base
    const int cp4 = isR ? gx0 : gx0 + 4;    // clamped right-load base

    // ring state (fully unrolled loop -> pure register renaming)
    float hm0a[10], hm0b[10], mn0p[8];
    float hx0a[8], hx0b[8];
    float x0a[8], x0b[8];
    float hm1a[6], hm1b[6], mn1p[4];
    float hx1a[4], hx1b[4];
    float x1a[4], x1b[4];

    #pragma unroll
    for (int i = 0; i < 10; ++i) { hm0a[i] = INFINITY; hm0b[i] = INFINITY; }
    #pragma unroll
    for (int j = 0; j < 8; ++j)  { mn0p[j] = -INFINITY; hx0a[j] = -INFINITY; hx0b[j] = -INFINITY; x0a[j] = INFINITY; x0b[j] = INFINITY; }
    #pragma unroll
    for (int k = 0; k < 6; ++k)  { hm1a[k] = INFINITY; hm1b[k] = INFINITY; }
    #pragma unroll
    for (int m = 0; m < 4; ++m)  { mn1p[m] = -INFINITY; hx1a[m] = -INFINITY; hx1b[m] = -INFINITY; x1a[m] = INFINITY; x1b[m] = INFINITY; }

    float acc0 = 0.0f, acc1 = 0.0f;

    // depth-3 prefetch: xA = row R, xB = R+1, xC = R+2, xD loaded for R+3
    float xA[12], xB[12], xC[12];
    loadrowC(img, y0 - 4, cm4, gx0, cp4, isL, isR, xA);
    loadrowC(img, y0 - 3, cm4, gx0, cp4, isL, isR, xB);
    loadrowC(img, y0 - 2, cm4, gx0, cp4, isL, isR, xC);
    // depth-3 companion ring: cmpQ0 consumed at rr, cmpQ2 loaded at rr for rr+3
    float4 cmpQ0, cmpQ1, cmpQ2;
    cmpQ0.x = cmpQ0.y = cmpQ0.z = cmpQ0.w = 0.f;
    cmpQ1 = cmpQ0; cmpQ2 = cmpQ0;

    #pragma unroll
    for (int rr = 0; rr < CHUNK + 8; ++rr) {
        const int R = y0 - 4 + rr;

        float xD[12];
        if (rr < CHUNK + 5) {
            loadrowC(img, R + 3, cm4, gx0, cp4, isL, isR, xD);
        } else {
            #pragma unroll
            for (int i = 0; i < 12; ++i) xD[i] = INFINITY;  // dead, DCE'd
        }

        float4 cmpCur;
        if (FUSED) {
            cmpCur = cmpQ0;
            cmpQ0 = cmpQ1; cmpQ1 = cmpQ2;                    // free after unroll
            if (rr >= 5 && rr < CHUNK + 5) {
                // row (R-1) = output row consumed 3 iterations later (in-range)
                cmpQ2 = *(const float4*)(cmp + (size_t)(R - 1) * WW + gx0);
            }
        }

        // ---- iter1 horizontal min, row R ----
        float hm0c[10];
        #pragma unroll
        for (int i = 0; i < 10; ++i) hm0c[i] = min3f(xA[i], xA[i + 1], xA[i + 2]);

        // ---- iter1 min-pool row R-1 ----
        float mn0n[10];
        #pragma unroll
        for (int i = 0; i < 10; ++i) mn0n[i] = min3f(hm0a[i], hm0b[i], hm0c[i]);
        if (!((unsigned)(R - 1) < HH)) {        // wave-uniform, rarely taken
            #pragma unroll
            for (int i = 0; i < 10; ++i) mn0n[i] = -INFINITY;
        }
        if (isL) { mn0n[0] = -INFINITY; mn0n[1] = -INFINITY; mn0n[2] = -INFINITY; }
        if (isR) { mn0n[7] = -INFINITY; mn0n[8] = -INFINITY; mn0n[9] = -INFINITY; }

        // ---- horiz max of mn0 row R-1 ----
        float hx0n[8];
        #pragma unroll
        for (int j = 0; j < 8; ++j) hx0n[j] = max3f(mn0n[j], mn0n[j + 1], mn0n[j + 2]);

        // ---- iter1 update: x1 row R-2 ----
        float x1n[8];
        #pragma unroll
        for (int j = 0; j < 8; ++j) {
            float mp = max3f(hx0a[j], hx0b[j], hx0n[j]);
            float ct = fmaxf(mp - mn0p[j], 0.0f);
            x1n[j] = fmaxf(x0a[j] - ct, 0.0f);
        }
        if (!((unsigned)(R - 2) < HH)) {
            #pragma unroll
            for (int j = 0; j < 8; ++j) x1n[j] = INFINITY;
        }
        if (isL) { x1n[0] = INFINITY; x1n[1] = INFINITY; }
        if (isR) { x1n[6] = INFINITY; x1n[7] = INFINITY; }

        // ---- iter2 horizontal min, row R-2 ----
        float hm1n[6];
        #pragma unroll
        for (int k = 0; k < 6; ++k) hm1n[k] = min3f(x1n[k], x1n[k + 1], x1n[k + 2]);

        // ---- iter2 min-pool row R-3 ----
        float mn1n[6];
        #pragma unroll
        for (int k = 0; k < 6; ++k) mn1n[k] = min3f(hm1a[k], hm1b[k], hm1n[k]);
        if (!((unsigned)(R - 3) < HH)) {
            #pragma unroll
            for (int k = 0; k < 6; ++k) mn1n[k] = -INFINITY;
        }
        if (isL) mn1n[0] = -INFINITY;
        if (isR) mn1n[5] = -INFINITY;

        // ---- horiz max of mn1 row R-3 ----
        float hx1n[4];
        #pragma unroll
        for (int m = 0; m < 4; ++m) hx1n[m] = max3f(mn1n[m], mn1n[m + 1], mn1n[m + 2]);

        // ---- iter2 update: x2 row R-4 ----
        if (rr >= 8) {
            float o[4];
            #pragma unroll
            for (int m = 0; m < 4; ++m) {
                float mp = max3f(hx1a[m], hx1b[m], hx1n[m]);
                float ct = fmaxf(mp - mn1p[m], 0.0f);
                o[m] = fmaxf(x1a[m] - ct, 0.0f);
            }
            if (FUSED) {
                acc0 += o[0] * cmpCur.x + o[1] * cmpCur.y + o[2] * cmpCur.z + o[3] * cmpCur.w;
                acc1 += o[0] + o[1] + o[2] + o[3];
            } else {
                float4 ov;
                ov.x = o[0]; ov.y = o[1]; ov.z = o[2]; ov.w = o[3];
                *(float4*)(outp + (size_t)(R - 4) * WW + gx0) = ov;
            }
        }

        // ---- ring shifts (free after full unroll) ----
        #pragma unroll
        for (int i = 0; i < 10; ++i) { hm0a[i] = hm0b[i]; hm0b[i] = hm0c[i]; }
        #pragma unroll
        for (int j = 0; j < 8; ++j)  { mn0p[j] = mn0n[j + 1]; hx0a[j] = hx0b[j]; hx0b[j] = hx0n[j]; x0a[j] = x0b[j]; x0b[j] = xA[j + 2]; }
        #pragma unroll
        for (int k = 0; k < 6; ++k)  { hm1a[k] = hm1b[k]; hm1b[k] = hm1n[k]; }
        #pragma unroll
        for (int m = 0; m < 4; ++m)  { mn1p[m] = mn1n[m + 1]; hx1a[m] = hx1b[m]; hx1b[m] = hx1n[m]; x1a[m] = x1b[m]; x1b[m] = x1n[m + 2]; }
        #pragma unroll
        for (int i = 0; i < 12; ++i) { xA[i] = xB[i]; xB[i] = xC[i]; xC[i] = xD[i]; }
    }

    if (FUSED) {
        for (int off = 32; off; off >>= 1) {
            acc0 += __shfl_down(acc0, off);
            acc1 += __shfl_down(acc1, off);
        }
        __shared__ float red[4][2];
        if (threadIdx.x == 0) { red[threadIdx.y][0] = acc0; red[threadIdx.y][1] = acc1; }
        __syncthreads();
        if (threadIdx.x == 0 && threadIdx.y == 0) {
            const int tile = blockIdx.x * gridDim.y + blockIdx.y;  // 0..7
            float* p = partials + ((size_t)z * 16 + tile) * 2;
            p[0] = red[0][0] + red[1][0] + red[2][0] + red[3][0];
            p[1] = red[0][1] + red[1][1] + red[2][1] + red[3][1];
        }
    }
}

// partials layout: [z][16 tile slots][2] (only first ntiles used per z);
// z<32: (sum clp*tgt, sum clp); z>=32: (sum skt*prd, sum skt)
__global__ __launch_bounds__(64) void finalize2(const float* __restrict__ partials,
                                                int ntiles,
                                                float* __restrict__ out) {
    const int b = threadIdx.x;
    float iflat = 0.f, tflat = 0.f;
    if (b < BB) {
        float v0 = 0.f, v1 = 0.f, v2 = 0.f, v3 = 0.f;
        for (int t = 0; t < ntiles; ++t) {
            v0 += partials[((size_t)b * 16 + t) * 2 + 0];
            v1 += partials[((size_t)b * 16 + t) * 2 + 1];
            v2 += partials[((size_t)(b + BB) * 16 + t) * 2 + 0];
            v3 += partials[((size_t)(b + BB) * 16 + t) * 2 + 1];
        }
        iflat = (v0 + 1e-6f) / (v1 + 1e-6f);
        tflat = (v2 + 1e-6f) / (v3 + 1e-6f);
    }
    float prod = iflat * tflat;
    float ssum = iflat + tflat;
    for (int off = 32; off; off >>= 1) {
        prod += __shfl_down(prod, off);
        ssum += __shfl_down(ssum, off);
    }
    if (threadIdx.x == 0) out[0] = 1.0f - 2.0f * prod / ssum;
}

extern "C" void kernel_launch(void* const* d_in, const int* in_sizes, int n_in,
                              void* d_out, int out_size, void* d_ws, size_t ws_size,
                              hipStream_t stream) {
    const float* pred = (const float*)d_in[0];
    const float* target = (const float*)d_in[1];
    float* out = (float*)d_out;
    char* ws = (char*)d_ws;
    const size_t N = (size_t)HH * WW;
    const size_t HALF = (size_t)BB * N;                 // 32 imgs of floats
    const size_t IMG32 = HALF * sizeof(float);          // 32 MB

    dim3 block(64, 4);
    const int nby = HH / (CHUNK * 4);                   // 4
    const int ntiles = 2 * nby;                         // 8

    if (ws_size >= 4 * IMG32 + (1 << 16)) {
        // z=64 path: both chains per dispatch, ping-pong 64MB buffers A<->B
        float* A = (float*)ws;
        float* B = (float*)(ws + 2 * IMG32);
        float* partials = (float*)(ws + 4 * IMG32);     // 64*16*2 floats
        dim3 grid(2, nby, 2 * BB);
        skel2r_t<0><<<grid, block, 0, stream>>>(pred, target, nullptr, nullptr, A, nullptr);
        skel2r_t<0><<<grid, block, 0, stream>>>(A, A + HALF, nullptr, nullptr, B, nullptr);
        skel2r_t<0><<<grid, block, 0, stream>>>(B, B + HALF, nullptr, nullptr, A, nullptr);
        skel2r_t<0><<<grid, block, 0, stream>>>(A, A + HALF, nullptr, nullptr, B, nullptr);
        // final pass fused with reduction: z<32 companion=target, z>=32 companion=pred
        skel2r_t<1><<<grid, block, 0, stream>>>(B, B + HALF, target, pred, nullptr, partials);
        finalize2<<<1, 64, 0, stream>>>(partials, ntiles, out);
    } else {
        // fallback: z=32 path with 2x32MB buffers, fused final pass per chain
        float* b0 = (float*)ws;
        float* b1 = (float*)(ws + IMG32);
        float* partials = (float*)(ws + 2 * IMG32);
        dim3 grid(2, nby, BB);
        skel2r_t<0><<<grid, block, 0, stream>>>(pred, pred, nullptr, nullptr, b0, nullptr);
        skel2r_t<0><<<grid, block, 0, stream>>>(b0, b0, nullptr, nullptr, b1, nullptr);
        skel2r_t<0><<<grid, block, 0, stream>>>(b1, b1, nullptr, nullptr, b0, nullptr);
        skel2r_t<0><<<grid, block, 0, stream>>>(b0, b0, nullptr, nullptr, b1, nullptr);
        skel2r_t<1><<<grid, block, 0, stream>>>(b1, b1, target, target, nullptr, partials);
        skel2r_t<0><<<grid, block, 0, stream>>>(target, target, nullptr, nullptr, b0, nullptr);
        skel2r_t<0><<<grid, block, 0, stream>>>(b0, b0, nullptr, nullptr, b1, nullptr);
        skel2r_t<0><<<grid, block, 0, stream>>>(b1, b1, nullptr, nullptr, b0, nullptr);
        skel2r_t<0><<<grid, block, 0, stream>>>(b0, b0, nullptr, nullptr, b1, nullptr);
        skel2r_t<1><<<grid, block, 0, stream>>>(b1, b1, pred, pred, nullptr,
                                                partials + (size_t)BB * 16 * 2);
        finalize2<<<1, 64, 0, stream>>>(partials, ntiles, out);
    }
}